// Round 10
// baseline (91.368 us; speedup 1.0000x reference)
//
#include <hip/hip_runtime.h>
#include <cstdint>

typedef uint16_t u16;
typedef __attribute__((ext_vector_type(8))) short short8;
typedef __attribute__((ext_vector_type(4))) float f32x4;

__device__ __forceinline__ u16 f2bf(float f) {
  uint32_t u = __float_as_uint(f);
  u += 0x7fff + ((u >> 16) & 1);   // RNE
  return (u16)(u >> 16);
}
// pack 2 floats -> 2 bf16 (round-half-up): a low, b high
__device__ __forceinline__ uint32_t pk2bf(float a, float b) {
  uint32_t ua = __float_as_uint(a) + 0x8000u;
  uint32_t ub = __float_as_uint(b) + 0x8000u;
  return (ua >> 16) | (ub & 0xFFFF0000u);
}

#define GLL16(gp, lp) __builtin_amdgcn_global_load_lds( \
    (__attribute__((address_space(1))) void*)(gp), \
    (__attribute__((address_space(3))) void*)(lp), 16, 0, 0)

#define SBAR()       __builtin_amdgcn_s_barrier()
#define WAIT_LGKM0() asm volatile("s_waitcnt lgkmcnt(0)" ::: "memory")
#define WAIT_VM(N)   asm volatile("s_waitcnt vmcnt(" #N ")" ::: "memory")
#define MEMBAR()     asm volatile("" ::: "memory")

// ---------------- fused f32 -> bf16 convert; Wq pre-scaled by d^-0.5 * log2(e) ----------------
__global__ void cvt_all(const float* __restrict__ x,  const float* __restrict__ wq,
                        const float* __restrict__ wk, const float* __restrict__ wv,
                        const float* __restrict__ wo,
                        u16* __restrict__ xb, u16* __restrict__ wcat, u16* __restrict__ wob) {
  int i = blockIdx.x * 256 + threadIdx.x;
  const float4* src; ushort4* dst; int off; float sc = 1.0f;
  if (i < 1048576)      { src = (const float4*)x;  dst = (ushort4*)xb;              off = i; }
  else if (i < 1310720) { src = (const float4*)wq; dst = (ushort4*)wcat;            off = i - 1048576;
                          sc = 0.18033688011112042f; }   // 0.125 * log2(e)
  else if (i < 1572864) { src = (const float4*)wk; dst = (ushort4*)wcat + 262144;   off = i - 1310720; }
  else if (i < 1835008) { src = (const float4*)wv; dst = (ushort4*)wcat + 524288;   off = i - 1572864; }
  else                  { src = (const float4*)wo; dst = (ushort4*)wob;             off = i - 1835008; }
  float4 v = src[off];
  ushort4 o;
  o.x = f2bf(v.x * sc); o.y = f2bf(v.y * sc); o.z = f2bf(v.z * sc); o.w = f2bf(v.w * sc);
  dst[off] = o;
}

// ---------------- 128x128 counted-vmcnt GEMM (unchanged) ----------------
template<int OUT_BF16>
__global__ __launch_bounds__(256, 2) void gemm128(const u16* __restrict__ A,
                                                  const u16* __restrict__ B,
                                                  void* __restrict__ Cout,
                                                  int N, int K, int ntN) {
  __shared__ u16 sm[2][2][128 * 64];
  const int tid  = threadIdx.x;
  const int lane = tid & 63, w = tid >> 6;
  const int wr = w >> 1, wc = w & 1;
  const int g = lane >> 4, lr = lane & 15;

  const int cpx = gridDim.x >> 3;
  const int id  = blockIdx.x;
  const int sw  = (id & 7) * cpx + (id >> 3);
  const int row0 = (sw / ntN) * 128, col0 = (sw % ntN) * 128;
  const int T = K >> 6;

  f32x4 acc[4][4];
  #pragma unroll
  for (int i = 0; i < 4; ++i)
    #pragma unroll
    for (int j = 0; j < 4; ++j) acc[i][j] = (f32x4){0.f, 0.f, 0.f, 0.f};

  auto STAGE = [&](int kt, int bufi) {
    #pragma unroll
    for (int ab = 0; ab < 2; ++ab) {
      const u16* __restrict__ src = ab ? B : A;
      const int rb = ab ? col0 : row0;
      #pragma unroll
      for (int j = 0; j < 4; ++j) {
        int r  = j * 32 + w * 8 + (lane >> 3);
        int sb = ((lane & 7) << 4) ^ ((r & 7) << 4);
        const u16* gp = src + (size_t)(rb + r) * K + kt * 64 + (sb >> 1);
        GLL16(gp, &sm[bufi][ab][(size_t)(j * 32 + w * 8) * 64]);
      }
    }
  };

  STAGE(0, 0); STAGE(1, 1);
  WAIT_VM(8); SBAR(); MEMBAR();

  for (int t = 0; t < T; ++t) {
    const int cur = t & 1;
    short8 a[4][2], b[4][2];
    #pragma unroll
    for (int mm = 0; mm < 4; ++mm)
      #pragma unroll
      for (int kh = 0; kh < 2; ++kh) {
        int row = wr * 64 + mm * 16 + lr;
        int col = (kh * 64 + g * 16) ^ ((row & 7) << 4);
        a[mm][kh] = *(const short8*)((const char*)&sm[cur][0][0] + row * 128 + col);
      }
    #pragma unroll
    for (int nn = 0; nn < 4; ++nn)
      #pragma unroll
      for (int kh = 0; kh < 2; ++kh) {
        int row = wc * 64 + nn * 16 + lr;
        int col = (kh * 64 + g * 16) ^ ((row & 7) << 4);
        b[nn][kh] = *(const short8*)((const char*)&sm[cur][1][0] + row * 128 + col);
      }
    WAIT_LGKM0(); MEMBAR(); SBAR(); MEMBAR();

    if (t + 2 < T) STAGE(t + 2, cur);

    __builtin_amdgcn_s_setprio(1);
    #pragma unroll
    for (int kh = 0; kh < 2; ++kh)
      #pragma unroll
      for (int mm = 0; mm < 4; ++mm)
        #pragma unroll
        for (int nn = 0; nn < 4; ++nn)
          acc[mm][nn] = __builtin_amdgcn_mfma_f32_16x16x32_bf16(
              a[mm][kh], b[nn][kh], acc[mm][nn], 0, 0, 0);
    __builtin_amdgcn_s_setprio(0);

    if (t + 1 < T) {
      if (t + 2 < T) { WAIT_VM(8); } else { WAIT_VM(0); }
      SBAR(); MEMBAR();
    }
  }

  #pragma unroll
  for (int i = 0; i < 4; ++i)
    #pragma unroll
    for (int j = 0; j < 4; ++j)
      #pragma unroll
      for (int ri = 0; ri < 4; ++ri) {
        int rr = row0 + wr * 64 + i * 16 + g * 4 + ri;
        int cc = col0 + wc * 64 + j * 16 + lr;
        if (OUT_BF16) ((u16*)Cout)[(size_t)rr * N + cc] = f2bf(acc[i][j][ri]);
        else          ((float*)Cout)[(size_t)rr * N + cc] = acc[i][j][ri];
      }
}

// ---------------- Flash sliding-window attention (v6) ----------------
// v5 + single barrier per tile: Vt double-buffered; V global->reg loads issued oldest so
// WAIT_VM(2) frees them while K GLLs stay in flight; each wave waits ITS K GLLs (vmcnt(0),
// issue->wait spans the whole tile's compute) + lgkm0 before the one s_barrier that
// publishes Klds[nxt] + Vt[nxt]. No full-drain __syncthreads in the loop. 3 blocks/CU.
__global__ __launch_bounds__(256, 3) void attn_swa(const u16* __restrict__ QKV, u16* __restrict__ O) {
  const int S = 2048;
  const int qb = blockIdx.x * 128;
  const int b = blockIdx.y >> 4, h = blockIdx.y & 15;
  const int tid = threadIdx.x;
  const int lane = tid & 63, w = tid >> 6;
  const int g = lane >> 4, lr = lane & 15;

  __shared__ u16 Klds[2][64 * 64];   // [64 keys][64 d], rows 128B, byte ^= (row&7)<<4
  __shared__ u16 Vt[2][64][72];      // V^T [d][key], pitch 144B, double-buffered
  __shared__ u16 Plds[4][32][72];    // per-wave P^T [q 0..31][key 0..63], pitch 144B
  // total LDS = 16384 + 18432 + 18432 = 53248 B -> 3 blocks/CU

  const u16* Qb = QKV + (size_t)b * S * 3072 + h * 64;
  const u16* Kb = QKV + (size_t)b * S * 3072 + 1024 + h * 64;
  const u16* Vb = QKV + (size_t)b * S * 3072 + 2048 + h * 64;

  const int qw = qb + w * 32;
  short8 qf[2][2];
  #pragma unroll
  for (int qg = 0; qg < 2; ++qg)
    #pragma unroll
    for (int kh = 0; kh < 2; ++kh)
      qf[qg][kh] = *(const short8*)(Qb + (size_t)(qw + qg * 16 + lr) * 3072 + kh * 32 + g * 8);

  float ls[2] = {0.f, 0.f};
  f32x4 accO[2][4];
  #pragma unroll
  for (int qg = 0; qg < 2; ++qg)
    #pragma unroll
    for (int i = 0; i < 4; ++i) accO[qg][i] = (f32x4){0.f, 0.f, 0.f, 0.f};

  int ks = qb - 511; if (ks < 0) ks = 0; ks &= ~63;
  const int ke = qb + 127;
  const int nt = ((ke - ks) >> 6) + 1;

  short8 vreg0, vreg1;

  auto STAGE_K = [&](int kb, int buf) {
    #pragma unroll
    for (int c = 0; c < 2; ++c) {
      int r  = c * 32 + w * 8 + (lane >> 3);
      int sb = ((lane & 7) << 4) ^ ((r & 7) << 4);
      const u16* gp = Kb + (size_t)(kb + r) * 3072 + (sb >> 1);
      u16* lp = Klds[buf] + c * 2048 + w * 512;
      GLL16(gp, lp);
    }
  };
  auto LOAD_V = [&](int kb) {
    vreg0 = *(const short8*)(Vb + (size_t)(kb + lane) * 3072 + w * 8);
    vreg1 = *(const short8*)(Vb + (size_t)(kb + lane) * 3072 + w * 8 + 32);
  };
  auto WRITE_V = [&](int buf) {
    #pragma unroll
    for (int j = 0; j < 8; ++j) Vt[buf][w * 8 + j][lane]      = (u16)vreg0[j];
    #pragma unroll
    for (int j = 0; j < 8; ++j) Vt[buf][w * 8 + 32 + j][lane] = (u16)vreg1[j];
  };

  // prologue: V loads issued first (oldest), then K GLLs
  LOAD_V(ks); MEMBAR();
  STAGE_K(ks, 0); MEMBAR();
  WAIT_VM(2); MEMBAR();    // V regs ready; K GLLs still in flight
  WRITE_V(0);
  WAIT_VM(0); WAIT_LGKM0(); MEMBAR();
  SBAR(); MEMBAR();

  int cur = 0, kb = ks;
  for (int t = 0; t < nt; ++t, kb += 64) {
    const int nxt = cur ^ 1;
    const bool more = (t + 1 < nt);
    if (more) { LOAD_V(kb + 64); MEMBAR(); STAGE_K(kb + 64, nxt); MEMBAR(); }

    // ---- QK^T (swapped): per key-subtile read K-frags once, 4 MFMAs (2 kh x 2 qg) ----
    float p[2][4][4];
    #pragma unroll
    for (int st = 0; st < 4; ++st) {
      f32x4 c4[2];
      c4[0] = (f32x4){0.f, 0.f, 0.f, 0.f};
      c4[1] = (f32x4){0.f, 0.f, 0.f, 0.f};
      int r = st * 16 + lr;
      int swz = (r & 7) << 4;
      const char* krow = (const char*)(Klds[cur]) + r * 128;
      short8 kf0 = *(const short8*)(krow + ((g * 16) ^ swz));
      short8 kf1 = *(const short8*)(krow + ((64 + g * 16) ^ swz));
      __builtin_amdgcn_s_setprio(1);
      c4[0] = __builtin_amdgcn_mfma_f32_16x16x32_bf16(kf0, qf[0][0], c4[0], 0, 0, 0);
      c4[1] = __builtin_amdgcn_mfma_f32_16x16x32_bf16(kf0, qf[1][0], c4[1], 0, 0, 0);
      c4[0] = __builtin_amdgcn_mfma_f32_16x16x32_bf16(kf1, qf[0][1], c4[0], 0, 0, 0);
      c4[1] = __builtin_amdgcn_mfma_f32_16x16x32_bf16(kf1, qf[1][1], c4[1], 0, 0, 0);
      __builtin_amdgcn_s_setprio(0);
      #pragma unroll
      for (int ri = 0; ri < 4; ++ri) { p[0][st][ri] = c4[0][ri]; p[1][st][ri] = c4[1][ri]; }
    }

    // ---- exp2 + mask (clean fast path per query group) + row sums + P^T -> LDS ----
    #pragma unroll
    for (int qg = 0; qg < 2; ++qg) {
      const int q0 = qw + qg * 16;
      const bool clean = (kb + 63 <= q0) && (q0 + 15 - kb < 512);
      if (clean) {
        #pragma unroll
        for (int st = 0; st < 4; ++st)
          #pragma unroll
          for (int ri = 0; ri < 4; ++ri)
            p[qg][st][ri] = __builtin_amdgcn_exp2f(p[qg][st][ri]);
      } else {
        const int base = q0 + lr - kb;
        #pragma unroll
        for (int st = 0; st < 4; ++st)
          #pragma unroll
          for (int ri = 0; ri < 4; ++ri) {
            float e = __builtin_amdgcn_exp2f(p[qg][st][ri]);
            p[qg][st][ri] = ((uint32_t)(base - (st * 16 + g * 4 + ri)) < 512u) ? e : 0.f;
          }
      }
      float s = 0.f;
      #pragma unroll
      for (int st = 0; st < 4; ++st)
        #pragma unroll
        for (int ri = 0; ri < 4; ++ri) s += p[qg][st][ri];
      s += __shfl_xor(s, 16);
      s += __shfl_xor(s, 32);
      ls[qg] += s;

      #pragma unroll
      for (int st = 0; st < 4; ++st) {
        uint2 u2;
        u2.x = pk2bf(p[qg][st][0], p[qg][st][1]);
        u2.y = pk2bf(p[qg][st][2], p[qg][st][3]);
        *(uint2*)(&Plds[w][qg * 16 + lr][st * 16 + g * 4]) = u2;
      }
    }

    // ---- PV: V-frags shared across qg ----
    short8 pf[2][2];
    #pragma unroll
    for (int qg = 0; qg < 2; ++qg) {
      pf[qg][0] = *(const short8*)(&Plds[w][qg * 16 + lr][g * 8]);
      pf[qg][1] = *(const short8*)(&Plds[w][qg * 16 + lr][32 + g * 8]);
    }
    __builtin_amdgcn_s_setprio(1);
    #pragma unroll
    for (int dt = 0; dt < 4; ++dt) {
      short8 vf0 = *(const short8*)(&Vt[cur][dt * 16 + lr][g * 8]);
      short8 vf1 = *(const short8*)(&Vt[cur][dt * 16 + lr][32 + g * 8]);
      accO[0][dt] = __builtin_amdgcn_mfma_f32_16x16x32_bf16(pf[0][0], vf0, accO[0][dt], 0, 0, 0);
      accO[1][dt] = __builtin_amdgcn_mfma_f32_16x16x32_bf16(pf[1][0], vf0, accO[1][dt], 0, 0, 0);
      accO[0][dt] = __builtin_amdgcn_mfma_f32_16x16x32_bf16(pf[0][1], vf1, accO[0][dt], 0, 0, 0);
      accO[1][dt] = __builtin_amdgcn_mfma_f32_16x16x32_bf16(pf[1][1], vf1, accO[1][dt], 0, 0, 0);
    }
    __builtin_amdgcn_s_setprio(0);

    // ---- end-of-tile: counted waits + ONE barrier ----
    if (more) {
      WAIT_VM(2); MEMBAR();        // V regs for t+1 ready (K GLLs still in flight)
      WRITE_V(nxt);
      WAIT_VM(0); WAIT_LGKM0(); MEMBAR();   // own K(t+1) GLLs + V ds_writes done
      SBAR(); MEMBAR();            // publish Klds[nxt] + Vt[nxt]
    }
    cur = nxt;
  }

  #pragma unroll
  for (int qg = 0; qg < 2; ++qg) {
    float lsq[4];
    #pragma unroll
    for (int ri = 0; ri < 4; ++ri) lsq[ri] = __shfl(ls[qg], g * 4 + ri);
    #pragma unroll
    for (int dt = 0; dt < 4; ++dt)
      #pragma unroll
      for (int ri = 0; ri < 4; ++ri) {
        int qi = qw + qg * 16 + g * 4 + ri;
        O[(size_t)(b * S + qi) * 1024 + h * 64 + dt * 16 + lr] = f2bf(accO[qg][dt][ri] / lsq[ri]);
      }
  }
}

// ---------------- launch ----------------
extern "C" void kernel_launch(void* const* d_in, const int* in_sizes, int n_in,
                              void* d_out, int out_size, void* d_ws, size_t ws_size,
                              hipStream_t stream) {
  const float* x  = (const float*)d_in[0];
  const float* Wq = (const float*)d_in[1];
  const float* Wk = (const float*)d_in[2];
  const float* Wv = (const float*)d_in[3];
  const float* Wo = (const float*)d_in[4];

  char* ws = (char*)d_ws;
  u16* xb   = (u16*)(ws);                    //  8 MiB: x bf16 [4096][1024]
  u16* Wcat = (u16*)(ws + (8  << 20));       //  6 MiB: [Wq;Wk;Wv] bf16 [3072][1024]
  u16* Wob  = (u16*)(ws + (14 << 20));       //  2 MiB: Wo bf16 [1024][1024]
  u16* QKV  = (u16*)(ws + (16 << 20));       // 24 MiB: [4096][3072]
  u16* Oatt = (u16*)(ws + (40 << 20));       //  8 MiB: [4096][1024]

  cvt_all<<<8192, 256, 0, stream>>>(x, Wq, Wk, Wv, Wo, xb, Wcat, Wob);
  gemm128<1><<<768, 256, 0, stream>>>(xb, Wcat, QKV, 3072, 1024, 24);
  attn_swa<<<dim3(16, 32), 256, 0, stream>>>(QKV, Oatt);
  gemm128<0><<<256, 256, 0, stream>>>(Oatt, Wob, d_out, 1024, 1024, 8);
}

// Round 11
// 89.763 us; speedup vs baseline: 1.0179x; 1.0179x over previous
//
#include <hip/hip_runtime.h>
#include <cstdint>

typedef uint16_t u16;
typedef __attribute__((ext_vector_type(8))) short short8;
typedef __attribute__((ext_vector_type(4))) float f32x4;

__device__ __forceinline__ u16 f2bf(float f) {
  uint32_t u = __float_as_uint(f);
  u += 0x7fff + ((u >> 16) & 1);   // RNE
  return (u16)(u >> 16);
}
// pack 2 floats -> 2 bf16 (round-half-up): a low, b high
__device__ __forceinline__ uint32_t pk2bf(float a, float b) {
  uint32_t ua = __float_as_uint(a) + 0x8000u;
  uint32_t ub = __float_as_uint(b) + 0x8000u;
  return (ua >> 16) | (ub & 0xFFFF0000u);
}

#define GLL16(gp, lp) __builtin_amdgcn_global_load_lds( \
    (__attribute__((address_space(1))) void*)(gp), \
    (__attribute__((address_space(3))) void*)(lp), 16, 0, 0)

#define SBAR()       __builtin_amdgcn_s_barrier()
#define WAIT_LGKM0() asm volatile("s_waitcnt lgkmcnt(0)" ::: "memory")
#define WAIT_VM(N)   asm volatile("s_waitcnt vmcnt(" #N ")" ::: "memory")
#define MEMBAR()     asm volatile("" ::: "memory")

// ---------------- fused f32 -> bf16 convert; Wq pre-scaled by d^-0.5 * log2(e) ----------------
__global__ void cvt_all(const float* __restrict__ x,  const float* __restrict__ wq,
                        const float* __restrict__ wk, const float* __restrict__ wv,
                        const float* __restrict__ wo,
                        u16* __restrict__ xb, u16* __restrict__ wcat, u16* __restrict__ wob) {
  int i = blockIdx.x * 256 + threadIdx.x;
  const float4* src; ushort4* dst; int off; float sc = 1.0f;
  if (i < 1048576)      { src = (const float4*)x;  dst = (ushort4*)xb;              off = i; }
  else if (i < 1310720) { src = (const float4*)wq; dst = (ushort4*)wcat;            off = i - 1048576;
                          sc = 0.18033688011112042f; }   // 0.125 * log2(e)
  else if (i < 1572864) { src = (const float4*)wk; dst = (ushort4*)wcat + 262144;   off = i - 1310720; }
  else if (i < 1835008) { src = (const float4*)wv; dst = (ushort4*)wcat + 524288;   off = i - 1572864; }
  else                  { src = (const float4*)wo; dst = (ushort4*)wob;             off = i - 1835008; }
  float4 v = src[off];
  ushort4 o;
  o.x = f2bf(v.x * sc); o.y = f2bf(v.y * sc); o.z = f2bf(v.z * sc); o.w = f2bf(v.w * sc);
  dst[off] = o;
}

// ---------------- BMx128 counted-vmcnt GEMM: C[m][n] = sum_k A[m][k]*B[n][k] ----------------
// BM=128: 4 waves 2x2, wave 64x64 (QKV, 768 blocks = 3/CU-pair). BM=64: wave 32x64,
// 512 blocks = 2/CU for the proj shape (M*N small -> need more blocks for TLP).
template<int BM, int OUT_BF16>
__global__ __launch_bounds__(256, 2) void gemm_t(const u16* __restrict__ A,
                                                 const u16* __restrict__ B,
                                                 void* __restrict__ Cout,
                                                 int N, int K, int ntN) {
  constexpr int MF = BM / 32;          // m-frags per wave
  __shared__ u16 smA[2][BM * 64];
  __shared__ u16 smB[2][128 * 64];
  const int tid  = threadIdx.x;
  const int lane = tid & 63, w = tid >> 6;
  const int wr = w >> 1, wc = w & 1;
  const int g = lane >> 4, lr = lane & 15;

  const int cpx = gridDim.x >> 3;
  const int id  = blockIdx.x;
  const int sw  = (id & 7) * cpx + (id >> 3);
  const int row0 = (sw / ntN) * BM, col0 = (sw % ntN) * 128;
  const int T = K >> 6;

  f32x4 acc[MF][4];
  #pragma unroll
  for (int i = 0; i < MF; ++i)
    #pragma unroll
    for (int j = 0; j < 4; ++j) acc[i][j] = (f32x4){0.f, 0.f, 0.f, 0.f};

  auto STAGE = [&](int kt, int bufi) {
    #pragma unroll
    for (int j = 0; j < BM / 32; ++j) {
      int r  = j * 32 + w * 8 + (lane >> 3);
      int sb = ((lane & 7) << 4) ^ ((r & 7) << 4);
      GLL16(A + (size_t)(row0 + r) * K + kt * 64 + (sb >> 1),
            &smA[bufi][(size_t)(j * 32 + w * 8) * 64]);
    }
    #pragma unroll
    for (int j = 0; j < 4; ++j) {
      int r  = j * 32 + w * 8 + (lane >> 3);
      int sb = ((lane & 7) << 4) ^ ((r & 7) << 4);
      GLL16(B + (size_t)(col0 + r) * K + kt * 64 + (sb >> 1),
            &smB[bufi][(size_t)(j * 32 + w * 8) * 64]);
    }
  };
  auto WVM_STEADY = [&]() {   // wait: next tile landed, t+2's GLLs still in flight
    if constexpr (BM == 128) { WAIT_VM(8); } else { WAIT_VM(6); }
  };

  STAGE(0, 0); STAGE(1, 1);
  WVM_STEADY(); SBAR(); MEMBAR();

  for (int t = 0; t < T; ++t) {
    const int cur = t & 1;
    short8 a[MF][2], b[4][2];
    #pragma unroll
    for (int mm = 0; mm < MF; ++mm)
      #pragma unroll
      for (int kh = 0; kh < 2; ++kh) {
        int row = wr * (BM / 2) + mm * 16 + lr;
        int col = (kh * 64 + g * 16) ^ ((row & 7) << 4);
        a[mm][kh] = *(const short8*)((const char*)&smA[cur][0] + row * 128 + col);
      }
    #pragma unroll
    for (int nn = 0; nn < 4; ++nn)
      #pragma unroll
      for (int kh = 0; kh < 2; ++kh) {
        int row = wc * 64 + nn * 16 + lr;
        int col = (kh * 64 + g * 16) ^ ((row & 7) << 4);
        b[nn][kh] = *(const short8*)((const char*)&smB[cur][0] + row * 128 + col);
      }
    WAIT_LGKM0(); MEMBAR(); SBAR(); MEMBAR();   // all waves' reads of buf[cur] done

    if (t + 2 < T) STAGE(t + 2, cur);

    __builtin_amdgcn_s_setprio(1);
    #pragma unroll
    for (int kh = 0; kh < 2; ++kh)
      #pragma unroll
      for (int mm = 0; mm < MF; ++mm)
        #pragma unroll
        for (int nn = 0; nn < 4; ++nn)
          acc[mm][nn] = __builtin_amdgcn_mfma_f32_16x16x32_bf16(
              a[mm][kh], b[nn][kh], acc[mm][nn], 0, 0, 0);
    __builtin_amdgcn_s_setprio(0);

    if (t + 1 < T) {
      if (t + 2 < T) { WVM_STEADY(); } else { WAIT_VM(0); }
      SBAR(); MEMBAR();
    }
  }

  #pragma unroll
  for (int i = 0; i < MF; ++i)
    #pragma unroll
    for (int j = 0; j < 4; ++j)
      #pragma unroll
      for (int ri = 0; ri < 4; ++ri) {
        int rr = row0 + wr * (BM / 2) + i * 16 + g * 4 + ri;
        int cc = col0 + wc * 64 + j * 16 + lr;
        if (OUT_BF16) ((u16*)Cout)[(size_t)rr * N + cc] = f2bf(acc[i][j][ri]);
        else          ((float*)Cout)[(size_t)rr * N + cc] = acc[i][j][ri];
      }
}

// ---------------- Flash sliding-window attention (v7: + per-wave tile compute-skip) ----------------
// Block = 4 waves x 32 queries (QBLK=128). Wave w needs keys [qw-511, qw+31] only; on
// tiles fully outside, skip QK/softmax/PV (wave-uniform) but keep staging + barrier.
__global__ __launch_bounds__(256, 3) void attn_swa(const u16* __restrict__ QKV, u16* __restrict__ O) {
  const int S = 2048;
  const int qb = blockIdx.x * 128;
  const int b = blockIdx.y >> 4, h = blockIdx.y & 15;
  const int tid = threadIdx.x;
  const int lane = tid & 63, w = tid >> 6;
  const int g = lane >> 4, lr = lane & 15;

  __shared__ u16 Klds[2][64 * 64];   // [64 keys][64 d], rows 128B, byte ^= (row&7)<<4
  __shared__ u16 Vt[2][64][72];      // V^T [d][key], pitch 144B, double-buffered
  __shared__ u16 Plds[4][32][72];    // per-wave P^T [q 0..31][key 0..63], pitch 144B

  const u16* Qb = QKV + (size_t)b * S * 3072 + h * 64;
  const u16* Kb = QKV + (size_t)b * S * 3072 + 1024 + h * 64;
  const u16* Vb = QKV + (size_t)b * S * 3072 + 2048 + h * 64;

  const int qw = qb + w * 32;
  short8 qf[2][2];
  #pragma unroll
  for (int qg = 0; qg < 2; ++qg)
    #pragma unroll
    for (int kh = 0; kh < 2; ++kh)
      qf[qg][kh] = *(const short8*)(Qb + (size_t)(qw + qg * 16 + lr) * 3072 + kh * 32 + g * 8);

  float ls[2] = {0.f, 0.f};
  f32x4 accO[2][4];
  #pragma unroll
  for (int qg = 0; qg < 2; ++qg)
    #pragma unroll
    for (int i = 0; i < 4; ++i) accO[qg][i] = (f32x4){0.f, 0.f, 0.f, 0.f};

  int ks = qb - 511; if (ks < 0) ks = 0; ks &= ~63;
  const int ke = qb + 127;
  const int nt = ((ke - ks) >> 6) + 1;

  short8 vreg0, vreg1;

  auto STAGE_K = [&](int kb, int buf) {
    #pragma unroll
    for (int c = 0; c < 2; ++c) {
      int r  = c * 32 + w * 8 + (lane >> 3);
      int sb = ((lane & 7) << 4) ^ ((r & 7) << 4);
      const u16* gp = Kb + (size_t)(kb + r) * 3072 + (sb >> 1);
      u16* lp = Klds[buf] + c * 2048 + w * 512;
      GLL16(gp, lp);
    }
  };
  auto LOAD_V = [&](int kb) {
    vreg0 = *(const short8*)(Vb + (size_t)(kb + lane) * 3072 + w * 8);
    vreg1 = *(const short8*)(Vb + (size_t)(kb + lane) * 3072 + w * 8 + 32);
  };
  auto WRITE_V = [&](int buf) {
    #pragma unroll
    for (int j = 0; j < 8; ++j) Vt[buf][w * 8 + j][lane]      = (u16)vreg0[j];
    #pragma unroll
    for (int j = 0; j < 8; ++j) Vt[buf][w * 8 + 32 + j][lane] = (u16)vreg1[j];
  };

  // prologue: V loads issued first (oldest), then K GLLs
  LOAD_V(ks); MEMBAR();
  STAGE_K(ks, 0); MEMBAR();
  WAIT_VM(2); MEMBAR();
  WRITE_V(0);
  WAIT_VM(0); WAIT_LGKM0(); MEMBAR();
  SBAR(); MEMBAR();

  int cur = 0, kb = ks;
  for (int t = 0; t < nt; ++t, kb += 64) {
    const int nxt = cur ^ 1;
    const bool more = (t + 1 < nt);
    if (more) { LOAD_V(kb + 64); MEMBAR(); STAGE_K(kb + 64, nxt); MEMBAR(); }

    // per-wave compute skip: tile outside [qw-511, qw+31] contributes only masked zeros
    const bool active = (kb <= qw + 31) && (kb + 63 >= qw - 511);
    if (active) {
      // ---- QK^T (swapped): per key-subtile read K-frags once, 4 MFMAs (2 kh x 2 qg) ----
      float p[2][4][4];
      #pragma unroll
      for (int st = 0; st < 4; ++st) {
        f32x4 c4[2];
        c4[0] = (f32x4){0.f, 0.f, 0.f, 0.f};
        c4[1] = (f32x4){0.f, 0.f, 0.f, 0.f};
        int r = st * 16 + lr;
        int swz = (r & 7) << 4;
        const char* krow = (const char*)(Klds[cur]) + r * 128;
        short8 kf0 = *(const short8*)(krow + ((g * 16) ^ swz));
        short8 kf1 = *(const short8*)(krow + ((64 + g * 16) ^ swz));
        __builtin_amdgcn_s_setprio(1);
        c4[0] = __builtin_amdgcn_mfma_f32_16x16x32_bf16(kf0, qf[0][0], c4[0], 0, 0, 0);
        c4[1] = __builtin_amdgcn_mfma_f32_16x16x32_bf16(kf0, qf[1][0], c4[1], 0, 0, 0);
        c4[0] = __builtin_amdgcn_mfma_f32_16x16x32_bf16(kf1, qf[0][1], c4[0], 0, 0, 0);
        c4[1] = __builtin_amdgcn_mfma_f32_16x16x32_bf16(kf1, qf[1][1], c4[1], 0, 0, 0);
        __builtin_amdgcn_s_setprio(0);
        #pragma unroll
        for (int ri = 0; ri < 4; ++ri) { p[0][st][ri] = c4[0][ri]; p[1][st][ri] = c4[1][ri]; }
      }

      // ---- exp2 + mask (clean fast path per query group) + row sums + P^T -> LDS ----
      #pragma unroll
      for (int qg = 0; qg < 2; ++qg) {
        const int q0 = qw + qg * 16;
        const bool clean = (kb + 63 <= q0) && (q0 + 15 - kb < 512);
        if (clean) {
          #pragma unroll
          for (int st = 0; st < 4; ++st)
            #pragma unroll
            for (int ri = 0; ri < 4; ++ri)
              p[qg][st][ri] = __builtin_amdgcn_exp2f(p[qg][st][ri]);
        } else {
          const int base = q0 + lr - kb;
          #pragma unroll
          for (int st = 0; st < 4; ++st)
            #pragma unroll
            for (int ri = 0; ri < 4; ++ri) {
              float e = __builtin_amdgcn_exp2f(p[qg][st][ri]);
              p[qg][st][ri] = ((uint32_t)(base - (st * 16 + g * 4 + ri)) < 512u) ? e : 0.f;
            }
        }
        float s = 0.f;
        #pragma unroll
        for (int st = 0; st < 4; ++st)
          #pragma unroll
          for (int ri = 0; ri < 4; ++ri) s += p[qg][st][ri];
        s += __shfl_xor(s, 16);
        s += __shfl_xor(s, 32);
        ls[qg] += s;

        #pragma unroll
        for (int st = 0; st < 4; ++st) {
          uint2 u2;
          u2.x = pk2bf(p[qg][st][0], p[qg][st][1]);
          u2.y = pk2bf(p[qg][st][2], p[qg][st][3]);
          *(uint2*)(&Plds[w][qg * 16 + lr][st * 16 + g * 4]) = u2;
        }
      }

      // ---- PV: V-frags shared across qg ----
      short8 pf[2][2];
      #pragma unroll
      for (int qg = 0; qg < 2; ++qg) {
        pf[qg][0] = *(const short8*)(&Plds[w][qg * 16 + lr][g * 8]);
        pf[qg][1] = *(const short8*)(&Plds[w][qg * 16 + lr][32 + g * 8]);
      }
      __builtin_amdgcn_s_setprio(1);
      #pragma unroll
      for (int dt = 0; dt < 4; ++dt) {
        short8 vf0 = *(const short8*)(&Vt[cur][dt * 16 + lr][g * 8]);
        short8 vf1 = *(const short8*)(&Vt[cur][dt * 16 + lr][32 + g * 8]);
        accO[0][dt] = __builtin_amdgcn_mfma_f32_16x16x32_bf16(pf[0][0], vf0, accO[0][dt], 0, 0, 0);
        accO[1][dt] = __builtin_amdgcn_mfma_f32_16x16x32_bf16(pf[1][0], vf0, accO[1][dt], 0, 0, 0);
        accO[0][dt] = __builtin_amdgcn_mfma_f32_16x16x32_bf16(pf[0][1], vf1, accO[0][dt], 0, 0, 0);
        accO[1][dt] = __builtin_amdgcn_mfma_f32_16x16x32_bf16(pf[1][1], vf1, accO[1][dt], 0, 0, 0);
      }
      __builtin_amdgcn_s_setprio(0);
    }

    // ---- end-of-tile: counted waits + ONE barrier ----
    if (more) {
      WAIT_VM(2); MEMBAR();        // V regs for t+1 ready (K GLLs still in flight)
      WRITE_V(nxt);
      WAIT_VM(0); WAIT_LGKM0(); MEMBAR();
      SBAR(); MEMBAR();            // publish Klds[nxt] + Vt[nxt]
    }
    cur = nxt;
  }

  #pragma unroll
  for (int qg = 0; qg < 2; ++qg) {
    float lsq[4];
    #pragma unroll
    for (int ri = 0; ri < 4; ++ri) lsq[ri] = __shfl(ls[qg], g * 4 + ri);
    #pragma unroll
    for (int dt = 0; dt < 4; ++dt)
      #pragma unroll
      for (int ri = 0; ri < 4; ++ri) {
        int qi = qw + qg * 16 + g * 4 + ri;
        O[(size_t)(b * S + qi) * 1024 + h * 64 + dt * 16 + lr] = f2bf(accO[qg][dt][ri] / lsq[ri]);
      }
  }
}

// ---------------- launch ----------------
extern "C" void kernel_launch(void* const* d_in, const int* in_sizes, int n_in,
                              void* d_out, int out_size, void* d_ws, size_t ws_size,
                              hipStream_t stream) {
  const float* x  = (const float*)d_in[0];
  const float* Wq = (const float*)d_in[1];
  const float* Wk = (const float*)d_in[2];
  const float* Wv = (const float*)d_in[3];
  const float* Wo = (const float*)d_in[4];

  char* ws = (char*)d_ws;
  u16* xb   = (u16*)(ws);                    //  8 MiB: x bf16 [4096][1024]
  u16* Wcat = (u16*)(ws + (8  << 20));       //  6 MiB: [Wq;Wk;Wv] bf16 [3072][1024]
  u16* Wob  = (u16*)(ws + (14 << 20));       //  2 MiB: Wo bf16 [1024][1024]
  u16* QKV  = (u16*)(ws + (16 << 20));       // 24 MiB: [4096][3072]
  u16* Oatt = (u16*)(ws + (40 << 20));       //  8 MiB: [4096][1024]

  cvt_all<<<8192, 256, 0, stream>>>(x, Wq, Wk, Wv, Wo, xb, Wcat, Wob);
  gemm_t<128, 1><<<768, 256, 0, stream>>>(xb, Wcat, QKV, 3072, 1024, 24);
  attn_swa<<<dim3(16, 32), 256, 0, stream>>>(QKV, Oatt);
  gemm_t<64, 0><<<512, 256, 0, stream>>>(Oatt, Wob, d_out, 1024, 1024, 8);
}

// Round 12
// 89.649 us; speedup vs baseline: 1.0192x; 1.0013x over previous
//
#include <hip/hip_runtime.h>
#include <cstdint>

typedef uint16_t u16;
typedef __attribute__((ext_vector_type(8))) short short8;
typedef __attribute__((ext_vector_type(4))) float f32x4;

__device__ __forceinline__ u16 f2bf(float f) {
  uint32_t u = __float_as_uint(f);
  u += 0x7fff + ((u >> 16) & 1);   // RNE
  return (u16)(u >> 16);
}
// pack 2 floats -> 2 bf16 (round-half-up): a low, b high
__device__ __forceinline__ uint32_t pk2bf(float a, float b) {
  uint32_t ua = __float_as_uint(a) + 0x8000u;
  uint32_t ub = __float_as_uint(b) + 0x8000u;
  return (ua >> 16) | (ub & 0xFFFF0000u);
}

#define GLL16(gp, lp) __builtin_amdgcn_global_load_lds( \
    (__attribute__((address_space(1))) void*)(gp), \
    (__attribute__((address_space(3))) void*)(lp), 16, 0, 0)

#define SBAR()       __builtin_amdgcn_s_barrier()
#define WAIT_LGKM0() asm volatile("s_waitcnt lgkmcnt(0)" ::: "memory")
#define WAIT_VM(N)   asm volatile("s_waitcnt vmcnt(" #N ")" ::: "memory")
#define MEMBAR()     asm volatile("" ::: "memory")

// ---------------- fused f32 -> bf16 convert; Wq pre-scaled by d^-0.5 * log2(e) ----------------
__global__ void cvt_all(const float* __restrict__ x,  const float* __restrict__ wq,
                        const float* __restrict__ wk, const float* __restrict__ wv,
                        const float* __restrict__ wo,
                        u16* __restrict__ xb, u16* __restrict__ wcat, u16* __restrict__ wob) {
  int i = blockIdx.x * 256 + threadIdx.x;
  const float4* src; ushort4* dst; int off; float sc = 1.0f;
  if (i < 1048576)      { src = (const float4*)x;  dst = (ushort4*)xb;              off = i; }
  else if (i < 1310720) { src = (const float4*)wq; dst = (ushort4*)wcat;            off = i - 1048576;
                          sc = 0.18033688011112042f; }   // 0.125 * log2(e)
  else if (i < 1572864) { src = (const float4*)wk; dst = (ushort4*)wcat + 262144;   off = i - 1310720; }
  else if (i < 1835008) { src = (const float4*)wv; dst = (ushort4*)wcat + 524288;   off = i - 1572864; }
  else                  { src = (const float4*)wo; dst = (ushort4*)wob;             off = i - 1835008; }
  float4 v = src[off];
  ushort4 o;
  o.x = f2bf(v.x * sc); o.y = f2bf(v.y * sc); o.z = f2bf(v.z * sc); o.w = f2bf(v.w * sc);
  dst[off] = o;
}

// ---------------- BMx128 counted-vmcnt GEMM (unchanged from round 11) ----------------
template<int BM, int OUT_BF16>
__global__ __launch_bounds__(256, 2) void gemm_t(const u16* __restrict__ A,
                                                 const u16* __restrict__ B,
                                                 void* __restrict__ Cout,
                                                 int N, int K, int ntN) {
  constexpr int MF = BM / 32;
  __shared__ u16 smA[2][BM * 64];
  __shared__ u16 smB[2][128 * 64];
  const int tid  = threadIdx.x;
  const int lane = tid & 63, w = tid >> 6;
  const int wr = w >> 1, wc = w & 1;
  const int g = lane >> 4, lr = lane & 15;

  const int cpx = gridDim.x >> 3;
  const int id  = blockIdx.x;
  const int sw  = (id & 7) * cpx + (id >> 3);
  const int row0 = (sw / ntN) * BM, col0 = (sw % ntN) * 128;
  const int T = K >> 6;

  f32x4 acc[MF][4];
  #pragma unroll
  for (int i = 0; i < MF; ++i)
    #pragma unroll
    for (int j = 0; j < 4; ++j) acc[i][j] = (f32x4){0.f, 0.f, 0.f, 0.f};

  auto STAGE = [&](int kt, int bufi) {
    #pragma unroll
    for (int j = 0; j < BM / 32; ++j) {
      int r  = j * 32 + w * 8 + (lane >> 3);
      int sb = ((lane & 7) << 4) ^ ((r & 7) << 4);
      GLL16(A + (size_t)(row0 + r) * K + kt * 64 + (sb >> 1),
            &smA[bufi][(size_t)(j * 32 + w * 8) * 64]);
    }
    #pragma unroll
    for (int j = 0; j < 4; ++j) {
      int r  = j * 32 + w * 8 + (lane >> 3);
      int sb = ((lane & 7) << 4) ^ ((r & 7) << 4);
      GLL16(B + (size_t)(col0 + r) * K + kt * 64 + (sb >> 1),
            &smB[bufi][(size_t)(j * 32 + w * 8) * 64]);
    }
  };
  auto WVM_STEADY = [&]() {
    if constexpr (BM == 128) { WAIT_VM(8); } else { WAIT_VM(6); }
  };

  STAGE(0, 0); STAGE(1, 1);
  WVM_STEADY(); SBAR(); MEMBAR();

  for (int t = 0; t < T; ++t) {
    const int cur = t & 1;
    short8 a[MF][2], b[4][2];
    #pragma unroll
    for (int mm = 0; mm < MF; ++mm)
      #pragma unroll
      for (int kh = 0; kh < 2; ++kh) {
        int row = wr * (BM / 2) + mm * 16 + lr;
        int col = (kh * 64 + g * 16) ^ ((row & 7) << 4);
        a[mm][kh] = *(const short8*)((const char*)&smA[cur][0] + row * 128 + col);
      }
    #pragma unroll
    for (int nn = 0; nn < 4; ++nn)
      #pragma unroll
      for (int kh = 0; kh < 2; ++kh) {
        int row = wc * 64 + nn * 16 + lr;
        int col = (kh * 64 + g * 16) ^ ((row & 7) << 4);
        b[nn][kh] = *(const short8*)((const char*)&smB[cur][0] + row * 128 + col);
      }
    WAIT_LGKM0(); MEMBAR(); SBAR(); MEMBAR();

    if (t + 2 < T) STAGE(t + 2, cur);

    __builtin_amdgcn_s_setprio(1);
    #pragma unroll
    for (int kh = 0; kh < 2; ++kh)
      #pragma unroll
      for (int mm = 0; mm < MF; ++mm)
        #pragma unroll
        for (int nn = 0; nn < 4; ++nn)
          acc[mm][nn] = __builtin_amdgcn_mfma_f32_16x16x32_bf16(
              a[mm][kh], b[nn][kh], acc[mm][nn], 0, 0, 0);
    __builtin_amdgcn_s_setprio(0);

    if (t + 1 < T) {
      if (t + 2 < T) { WVM_STEADY(); } else { WAIT_VM(0); }
      SBAR(); MEMBAR();
    }
  }

  #pragma unroll
  for (int i = 0; i < MF; ++i)
    #pragma unroll
    for (int j = 0; j < 4; ++j)
      #pragma unroll
      for (int ri = 0; ri < 4; ++ri) {
        int rr = row0 + wr * (BM / 2) + i * 16 + g * 4 + ri;
        int cc = col0 + wc * 64 + j * 16 + lr;
        if (OUT_BF16) ((u16*)Cout)[(size_t)rr * N + cc] = f2bf(acc[i][j][ri]);
        else          ((float*)Cout)[(size_t)rr * N + cc] = acc[i][j][ri];
      }
}

// ---------------- Flash sliding-window attention (v8: barrier BEFORE PV) ----------------
// Per tile: issue V-loads + K-GLLs(t+1) -> QK(t) -> softmax + P-write -> vm0+lgkm0 ->
// SBAR -> WRITE_V(t+1) -> PV(t). PV and the V ds_writes run post-barrier, off the
// serialized path. Race audit: Vt[nxt] writes published by B(t+1) before PV(t+1); iter
// t+1 writes Vt[cur] only after B(t+1), by which point all PV(t) reads drained (they
// precede each wave's lgkm0+SBAR). Barrier every tile (incl. last, to publish its V).
__global__ __launch_bounds__(256, 3) void attn_swa(const u16* __restrict__ QKV, u16* __restrict__ O) {
  const int S = 2048;
  const int qb = blockIdx.x * 128;
  const int b = blockIdx.y >> 4, h = blockIdx.y & 15;
  const int tid = threadIdx.x;
  const int lane = tid & 63, w = tid >> 6;
  const int g = lane >> 4, lr = lane & 15;

  __shared__ u16 Klds[2][64 * 64];   // [64 keys][64 d], rows 128B, byte ^= (row&7)<<4
  __shared__ u16 Vt[2][64][72];      // V^T [d][key], pitch 144B, double-buffered
  __shared__ u16 Plds[4][32][72];    // per-wave P^T [q 0..31][key 0..63], pitch 144B

  const u16* Qb = QKV + (size_t)b * S * 3072 + h * 64;
  const u16* Kb = QKV + (size_t)b * S * 3072 + 1024 + h * 64;
  const u16* Vb = QKV + (size_t)b * S * 3072 + 2048 + h * 64;

  const int qw = qb + w * 32;
  short8 qf[2][2];
  #pragma unroll
  for (int qg = 0; qg < 2; ++qg)
    #pragma unroll
    for (int kh = 0; kh < 2; ++kh)
      qf[qg][kh] = *(const short8*)(Qb + (size_t)(qw + qg * 16 + lr) * 3072 + kh * 32 + g * 8);

  float ls[2] = {0.f, 0.f};
  f32x4 accO[2][4];
  #pragma unroll
  for (int qg = 0; qg < 2; ++qg)
    #pragma unroll
    for (int i = 0; i < 4; ++i) accO[qg][i] = (f32x4){0.f, 0.f, 0.f, 0.f};

  int ks = qb - 511; if (ks < 0) ks = 0; ks &= ~63;
  const int ke = qb + 127;
  const int nt = ((ke - ks) >> 6) + 1;

  short8 vreg0, vreg1;

  auto STAGE_K = [&](int kb, int buf) {
    #pragma unroll
    for (int c = 0; c < 2; ++c) {
      int r  = c * 32 + w * 8 + (lane >> 3);
      int sb = ((lane & 7) << 4) ^ ((r & 7) << 4);
      const u16* gp = Kb + (size_t)(kb + r) * 3072 + (sb >> 1);
      u16* lp = Klds[buf] + c * 2048 + w * 512;
      GLL16(gp, lp);
    }
  };
  auto LOAD_V = [&](int kb) {
    vreg0 = *(const short8*)(Vb + (size_t)(kb + lane) * 3072 + w * 8);
    vreg1 = *(const short8*)(Vb + (size_t)(kb + lane) * 3072 + w * 8 + 32);
  };
  auto WRITE_V = [&](int buf) {
    #pragma unroll
    for (int j = 0; j < 8; ++j) Vt[buf][w * 8 + j][lane]      = (u16)vreg0[j];
    #pragma unroll
    for (int j = 0; j < 8; ++j) Vt[buf][w * 8 + 32 + j][lane] = (u16)vreg1[j];
  };

  // prologue: stage tile 0; publish Klds[0]; Vt[0] written post-barrier (published at B0)
  LOAD_V(ks); MEMBAR();
  STAGE_K(ks, 0); MEMBAR();
  WAIT_VM(0); MEMBAR();
  SBAR(); MEMBAR();
  WRITE_V(0);

  int cur = 0, kb = ks;
  for (int t = 0; t < nt; ++t, kb += 64) {
    const int nxt = cur ^ 1;
    const bool more = (t + 1 < nt);
    if (more) { LOAD_V(kb + 64); MEMBAR(); STAGE_K(kb + 64, nxt); MEMBAR(); }

    // per-wave compute skip: tile outside [qw-511, qw+31] contributes only masked zeros
    const bool active = (kb <= qw + 31) && (kb + 63 >= qw - 511);
    if (active) {
      // ---- QK^T (swapped): per key-subtile read K-frags once, 4 MFMAs (2 kh x 2 qg) ----
      float p[2][4][4];
      #pragma unroll
      for (int st = 0; st < 4; ++st) {
        f32x4 c4[2];
        c4[0] = (f32x4){0.f, 0.f, 0.f, 0.f};
        c4[1] = (f32x4){0.f, 0.f, 0.f, 0.f};
        int r = st * 16 + lr;
        int swz = (r & 7) << 4;
        const char* krow = (const char*)(Klds[cur]) + r * 128;
        short8 kf0 = *(const short8*)(krow + ((g * 16) ^ swz));
        short8 kf1 = *(const short8*)(krow + ((64 + g * 16) ^ swz));
        __builtin_amdgcn_s_setprio(1);
        c4[0] = __builtin_amdgcn_mfma_f32_16x16x32_bf16(kf0, qf[0][0], c4[0], 0, 0, 0);
        c4[1] = __builtin_amdgcn_mfma_f32_16x16x32_bf16(kf0, qf[1][0], c4[1], 0, 0, 0);
        c4[0] = __builtin_amdgcn_mfma_f32_16x16x32_bf16(kf1, qf[0][1], c4[0], 0, 0, 0);
        c4[1] = __builtin_amdgcn_mfma_f32_16x16x32_bf16(kf1, qf[1][1], c4[1], 0, 0, 0);
        __builtin_amdgcn_s_setprio(0);
        #pragma unroll
        for (int ri = 0; ri < 4; ++ri) { p[0][st][ri] = c4[0][ri]; p[1][st][ri] = c4[1][ri]; }
      }

      // ---- exp2 + mask + row sums + P^T -> LDS ----
      #pragma unroll
      for (int qg = 0; qg < 2; ++qg) {
        const int q0 = qw + qg * 16;
        const bool clean = (kb + 63 <= q0) && (q0 + 15 - kb < 512);
        if (clean) {
          #pragma unroll
          for (int st = 0; st < 4; ++st)
            #pragma unroll
            for (int ri = 0; ri < 4; ++ri)
              p[qg][st][ri] = __builtin_amdgcn_exp2f(p[qg][st][ri]);
        } else {
          const int base = q0 + lr - kb;
          #pragma unroll
          for (int st = 0; st < 4; ++st)
            #pragma unroll
            for (int ri = 0; ri < 4; ++ri) {
              float e = __builtin_amdgcn_exp2f(p[qg][st][ri]);
              p[qg][st][ri] = ((uint32_t)(base - (st * 16 + g * 4 + ri)) < 512u) ? e : 0.f;
            }
        }
        float s = 0.f;
        #pragma unroll
        for (int st = 0; st < 4; ++st)
          #pragma unroll
          for (int ri = 0; ri < 4; ++ri) s += p[qg][st][ri];
        s += __shfl_xor(s, 16);
        s += __shfl_xor(s, 32);
        ls[qg] += s;

        #pragma unroll
        for (int st = 0; st < 4; ++st) {
          uint2 u2;
          u2.x = pk2bf(p[qg][st][0], p[qg][st][1]);
          u2.y = pk2bf(p[qg][st][2], p[qg][st][3]);
          *(uint2*)(&Plds[w][qg * 16 + lr][st * 16 + g * 4]) = u2;
        }
      }
    }

    // ---- mid-tile sync: K(t+1) landed + own ds ops drained -> barrier ----
    if (more) { WAIT_VM(0); MEMBAR(); }
    WAIT_LGKM0(); MEMBAR();
    SBAR(); MEMBAR();            // publishes Klds[nxt], Vt[cur] (prev iter's writes), Plds
    if (more) WRITE_V(nxt);      // post-barrier: touches only Vt[nxt]

    if (active) {
      // ---- PV: A = P^T, B = V^T[cur]; V-frags shared across qg ----
      short8 pf[2][2];
      #pragma unroll
      for (int qg = 0; qg < 2; ++qg) {
        pf[qg][0] = *(const short8*)(&Plds[w][qg * 16 + lr][g * 8]);
        pf[qg][1] = *(const short8*)(&Plds[w][qg * 16 + lr][32 + g * 8]);
      }
      __builtin_amdgcn_s_setprio(1);
      #pragma unroll
      for (int dt = 0; dt < 4; ++dt) {
        short8 vf0 = *(const short8*)(&Vt[cur][dt * 16 + lr][g * 8]);
        short8 vf1 = *(const short8*)(&Vt[cur][dt * 16 + lr][32 + g * 8]);
        accO[0][dt] = __builtin_amdgcn_mfma_f32_16x16x32_bf16(pf[0][0], vf0, accO[0][dt], 0, 0, 0);
        accO[1][dt] = __builtin_amdgcn_mfma_f32_16x16x32_bf16(pf[1][0], vf0, accO[1][dt], 0, 0, 0);
        accO[0][dt] = __builtin_amdgcn_mfma_f32_16x16x32_bf16(pf[0][1], vf1, accO[0][dt], 0, 0, 0);
        accO[1][dt] = __builtin_amdgcn_mfma_f32_16x16x32_bf16(pf[1][1], vf1, accO[1][dt], 0, 0, 0);
      }
      __builtin_amdgcn_s_setprio(0);
    }
    cur = nxt;
  }

  #pragma unroll
  for (int qg = 0; qg < 2; ++qg) {
    float lsq[4];
    #pragma unroll
    for (int ri = 0; ri < 4; ++ri) lsq[ri] = __shfl(ls[qg], g * 4 + ri);
    #pragma unroll
    for (int dt = 0; dt < 4; ++dt)
      #pragma unroll
      for (int ri = 0; ri < 4; ++ri) {
        int qi = qw + qg * 16 + g * 4 + ri;
        O[(size_t)(b * S + qi) * 1024 + h * 64 + dt * 16 + lr] = f2bf(accO[qg][dt][ri] / lsq[ri]);
      }
  }
}

// ---------------- launch ----------------
extern "C" void kernel_launch(void* const* d_in, const int* in_sizes, int n_in,
                              void* d_out, int out_size, void* d_ws, size_t ws_size,
                              hipStream_t stream) {
  const float* x  = (const float*)d_in[0];
  const float* Wq = (const float*)d_in[1];
  const float* Wk = (const float*)d_in[2];
  const float* Wv = (const float*)d_in[3];
  const float* Wo = (const float*)d_in[4];

  char* ws = (char*)d_ws;
  u16* xb   = (u16*)(ws);                    //  8 MiB: x bf16 [4096][1024]
  u16* Wcat = (u16*)(ws + (8  << 20));       //  6 MiB: [Wq;Wk;Wv] bf16 [3072][1024]
  u16* Wob  = (u16*)(ws + (14 << 20));       //  2 MiB: Wo bf16 [1024][1024]
  u16* QKV  = (u16*)(ws + (16 << 20));       // 24 MiB: [4096][3072]
  u16* Oatt = (u16*)(ws + (40 << 20));       //  8 MiB: [4096][1024]

  cvt_all<<<8192, 256, 0, stream>>>(x, Wq, Wk, Wv, Wo, xb, Wcat, Wob);
  gemm_t<128, 1><<<768, 256, 0, stream>>>(xb, Wcat, QKV, 3072, 1024, 24);
  attn_swa<<<dim3(16, 32), 256, 0, stream>>>(QKV, Oatt);
  gemm_t<64, 0><<<512, 256, 0, stream>>>(Oatt, Wob, d_out, 1024, 1024, 8);
}